// Round 1
// baseline (2478.961 us; speedup 1.0000x reference)
//
#include <hip/hip_runtime.h>
#include <cstdint>

// mLstm  B=16, P=128, Q=256, D=128, H=128. fp32 in/out (verified R4/R5).
// R6: residency rewrite of the sequential kernel. Per-CU L2 streaming was the
// bound (1.22 MB/step re-read at ~42 B/cy). Now register-resident: tA(32f),
// WgT(32f), WrT(16f) per thread (=327KB/CU); LDS-resident: whs (135KB padded).
// Only WTp (768KB) streams per step. Barriers 11->6 via wave-local shfl
// reductions; padded LDS strides kill bank conflicts; per-step wht/Gp/pf are
// rotating register prefetches. All math fp32; __expf in softmax bulk.

__device__ __forceinline__ float bf2f(uint16_t u) {
  uint32_t x = ((uint32_t)u) << 16; float f; __builtin_memcpy(&f, &x, 4); return f;
}
__device__ __forceinline__ float load_in(const void* p, size_t i, int f32) {
  return f32 ? ((const float*)p)[i] : bf2f(((const uint16_t*)p)[i]);
}
__device__ __forceinline__ float frcp(float x) { return __builtin_amdgcn_rcpf(x); }

// ------------------------------------------------------------- detect kernel
__global__ void detect_kernel(const uint16_t* __restrict__ q16,
                              uint32_t* __restrict__ flag) {
  __shared__ int cnt;
  if (threadIdx.x == 0) cnt = 0;
  __syncthreads();
  int bad = 0;
  for (int i = threadIdx.x; i < 4096; i += 256) {
    int e = (q16[i] >> 7) & 0xFF;
    if (e > 0x8A) bad++;
  }
  atomicAdd(&cnt, bad);
  __syncthreads();
  if (threadIdx.x == 0) *flag = (cnt > 16) ? 1u : 0u;
}

// ------------------------------------------------- convert + transpose pack
// pf[262144]=p; WrT[k*128+j]=Wr[j][k]; wrb[128]; wew[128]; web[1];
// WgT[k*256+i]=Wg[i][k] (full; seq uses k<128); wgb[256];
// WTp k4-major float4 pack: WTp[k4*2048 + i*4 + c] = WT[k4*4+c][i],
//   WT[k][i] = k<256 ? Wih[i][k] : Whh[i][k-256];  bb[512]=bih+bhh.
__global__ void pack2(const void* __restrict__ p,
                      const void* __restrict__ Wr,  const void* __restrict__ Wrb_,
                      const void* __restrict__ Wew_, const void* __restrict__ Web_,
                      const void* __restrict__ Wg,
                      const void* __restrict__ Wih, const void* __restrict__ Whh,
                      const void* __restrict__ bih, const void* __restrict__ bhh,
                      float* __restrict__ pf,
                      float* __restrict__ WrT, float* __restrict__ wrb,
                      float* __restrict__ wew, float* __restrict__ web,
                      float* __restrict__ WgT, float* __restrict__ wgb,
                      float* __restrict__ WTp, float* __restrict__ bb,
                      const void* __restrict__ Wgb_,
                      const uint32_t* __restrict__ flag) {
  const int f32 = (int)*flag;
  long idx = (long)blockIdx.x * blockDim.x + threadIdx.x;
  if (idx < 262144) { pf[idx] = load_in(p, idx, f32); return; }
  idx -= 262144;
  if (idx < 16384) { int k = idx >> 7, j = idx & 127;
    WrT[idx] = load_in(Wr, (size_t)j * 128 + k, f32); return; }
  idx -= 16384;
  if (idx < 128) { wrb[idx] = load_in(Wrb_, idx, f32); return; }
  idx -= 128;
  if (idx < 128) { wew[idx] = load_in(Wew_, idx, f32); return; }
  idx -= 128;
  if (idx < 1) { web[0] = load_in(Web_, 0, f32); return; }
  idx -= 1;
  if (idx < 65536) { int k = idx >> 8, i = idx & 255;
    WgT[idx] = load_in(Wg, (size_t)i * 256 + k, f32); return; }
  idx -= 65536;
  if (idx < 256) { wgb[idx] = load_in(Wgb_, idx, f32); return; }
  idx -= 256;
  if (idx < 196608) {
    int k4 = idx >> 11, i = (idx >> 2) & 511, c = idx & 3;
    int k = k4 * 4 + c;
    WTp[idx] = (k < 256) ? load_in(Wih, (size_t)i * 256 + k, f32)
                         : load_in(Whh, (size_t)i * 128 + (k - 256), f32);
    return; }
  idx -= 196608;
  if (idx < 512) { bb[idx] = load_in(bih, idx, f32) + load_in(bhh, idx, f32); }
}

// ------------------------------------------------------------ small GEMM
// out[r][c] = sum_k A[r][k]*W[w_off + c*ldw + k] + bias[c];  K=128.
__global__ __launch_bounds__(256) void gemm_rw(const void* __restrict__ A, int lda,
                                               const void* __restrict__ W, int ldw,
                                               int w_off,
                                               const void* __restrict__ bias,
                                               float* __restrict__ out, int C,
                                               const uint32_t* __restrict__ flag) {
  __shared__ float A_l[16][128];
  __shared__ float W_l[64][129];
  const int f32 = (int)*flag;
  const int t = threadIdx.x;
  const int r0 = blockIdx.x * 16;
  for (int idx = t; idx < 16 * 128; idx += 256) {
    int rr = idx >> 7, kk = idx & 127;
    A_l[rr][kk] = load_in(A, (size_t)(r0 + rr) * lda + kk, f32);
  }
  const int c_l = t & 63, rg = t >> 6;
  for (int c0 = 0; c0 < C; c0 += 64) {
    __syncthreads();
    for (int idx = t; idx < 64 * 128; idx += 256) {
      int cc = idx >> 7, kk = idx & 127;
      W_l[cc][kk] = load_in(W, (size_t)w_off + (size_t)(c0 + cc) * ldw + kk, f32);
    }
    __syncthreads();
    float acc[4] = {0.f, 0.f, 0.f, 0.f};
    for (int k = 0; k < 128; k++) {
      float w = W_l[c_l][k];
#pragma unroll
      for (int x = 0; x < 4; x++) acc[x] = fmaf(A_l[rg * 4 + x][k], w, acc[x]);
    }
    float bv = load_in(bias, c0 + c_l, f32);
#pragma unroll
    for (int x = 0; x < 4; x++)
      out[(size_t)(r0 + rg * 4 + x) * C + c0 + c_l] = acc[x] + bv;
  }
}

// tA = tanh(whs), elementwise over 524288
__global__ void tanh_whs(const float* __restrict__ whs, float* __restrict__ tA) {
  int i = blockIdx.x * blockDim.x + threadIdx.x;
  tA[i] = tanhf(whs[i]);
}

// ---------------------------------------------------------- sequential kernel
// 16 blocks x 1024 threads (4 waves/SIMD, VGPR cap 128). 6 barriers/step.
// Padded LDS index helpers (conflict-free layouts):
#define TUIDX(j) ((((j) >> 5) * 36) + ((j) & 31))
#define SCIDX(q) ((((q) >> 5) * 36) + ((q) & 31))
#define AIDX(h)  ((((h) >> 5) * 36) + ((h) & 31))
#define HIDX(k)  ((((k) >> 4) * 20) + ((k) & 15))

__global__ __launch_bounds__(1024, 4) void mlstm_seq4(
    const float* __restrict__ pf,    // [16][128][128]
    const float* __restrict__ whs,   // [16][256][128]
    const float* __restrict__ tA_g,  // [16][256][128] = tanh(whs)
    const float* __restrict__ wht_g, // [16][128][128] = p@Wt^T+Wtb
    const float* __restrict__ Gp_g,  // [16][128][256] = Wg_p@p+Wgb
    const float* __restrict__ WrT,   // [128][128] (k-major)
    const float* __restrict__ wrb,   // [128]
    const float* __restrict__ wew,   // [128]
    const float* __restrict__ web,   // [1]
    const float* __restrict__ WgT,   // [256][256] k-major (k<128 used)
    const float* __restrict__ WTp,   // [96][512][4] k4-major float4 pack
    const float* __restrict__ bb,    // [512]
    float* __restrict__ out) {       // [16][128][128]
  const int b = blockIdx.x, t = threadIdx.x;

  __shared__ __align__(16) float whs_l[256 * 132];   // 135168 B, padded rows
  __shared__ __align__(16) float tu_s[144];
  __shared__ __align__(16) float wew_s[144];
  __shared__ __align__(16) float sc_s[296];
  __shared__ __align__(16) float alpha_s[144];
  __shared__ __align__(16) float xh_s[384];
  __shared__ __align__(16) float h_s[160];
  __shared__ __align__(16) float gates_s[512];

  const float* whs_b = whs + (size_t)b * 32768;
  const float* tA_b  = tA_g + (size_t)b * 32768;

  // pass thread mappings (reduction groups = consecutive lanes -> shfl)
  const int jA = t >> 3, kgA = t & 7;   // A: 128 j x 8 kg (16 k each)
  const int qB = t >> 2, hgB = t & 3;   // B: 256 q x 4 hg (32 h each)
  const int hD = t >> 3, qgD = t & 7;   // D: 128 h x 8 qg (32 q interleaved)
  const int iE = t >> 2, kgE = t & 3;   // E: 256 i x 4 kg (32 k each)
  const int iF = t >> 1, kgF = t & 1;   // F: 512 i x 2 kg (192 k each)

  // ---- LDS init
  for (int idx = t; idx < 32768; idx += 1024)
    whs_l[(idx >> 7) * 132 + (idx & 127)] = whs_b[idx];
  if (t < 128) wew_s[TUIDX(t)] = wew[t];
  if (t < 160) h_s[t] = 0.f;
  if (t < 128) xh_s[256 + t] = 0.f;

  // ---- register-resident weights (loop-invariant)
  float wA[16];
#pragma unroll
  for (int r = 0; r < 16; r++)
    wA[r] = WrT[(size_t)(kgA * 16 + r) * 128 + jA];
  float4 tB4[8];
#pragma unroll
  for (int jj = 0; jj < 8; jj++)
    tB4[jj] = *(const float4*)(tA_b + (size_t)qB * 128 + hgB * 32 + jj * 4);
  float wE[32];
#pragma unroll
  for (int r = 0; r < 32; r++)
    wE[r] = WgT[(size_t)(kgE * 32 + r) * 256 + iE];

  const float web_r = web[0];
  const float wrb_r = wrb[jA];          // used by kgA==0 owners
  const float bb_r  = bb[iF];           // used by kgF==0 owners
  float c_r = 0.f;                      // LSTM c state, owners t<128

  // precomputed per-thread bases
  const float* whs_p = whs_l + qgD * 132 + hD;   // + r*1056
  const float* sc_pD = sc_s + qgD;               // + (r>>2)*36 + (r&3)*8
  const float* tu_pB = tu_s + hgB * 36;
  const float* we_pB = wew_s + hgB * 36;
  const float* al_pE = alpha_s + kgE * 36;
  const int aIdxE = AIDX(iE & 127);

  // per-step prefetch registers (rotate)
  float wht_c = (kgA == 0) ? wht_g[((size_t)b * 128 + 0) * 128 + jA] : 0.f;
  float gp_c  = (kgE == 0) ? Gp_g[((size_t)b * 128 + 0) * 256 + iE] : 0.f;
  float pf_c  = (kgE == 0 && iE >= 128) ? pf[((size_t)b * 128 + 0) * 128 + (iE - 128)] : 0.f;

  __syncthreads();

  for (int st = 0; st < 128; st++) {
    const int st1 = (st < 127) ? st + 1 : 127;
    float wht_n = (kgA == 0) ? wht_g[((size_t)b * 128 + st1) * 128 + jA] : 0.f;
    float gp_n  = (kgE == 0) ? Gp_g[((size_t)b * 128 + st1) * 256 + iE] : 0.f;
    float pf_n  = (kgE == 0 && iE >= 128) ? pf[((size_t)b * 128 + st1) * 128 + (iE - 128)] : 0.f;

    // ---- A: u = h @ Wr^T + wrb + wht ; tu = tanh(u)
    {
      float acc = 0.f;
#pragma unroll
      for (int rr = 0; rr < 4; rr++) {
        float4 h4 = *(const float4*)(h_s + kgA * 20 + rr * 4);
        acc = fmaf(h4.x, wA[rr * 4 + 0], acc);
        acc = fmaf(h4.y, wA[rr * 4 + 1], acc);
        acc = fmaf(h4.z, wA[rr * 4 + 2], acc);
        acc = fmaf(h4.w, wA[rr * 4 + 3], acc);
      }
      acc += __shfl_xor(acc, 1);
      acc += __shfl_xor(acc, 2);
      acc += __shfl_xor(acc, 4);
      if (kgA == 0) tu_s[TUIDX(jA)] = tanhf(acc + wrb_r + wht_c);
    }
    __syncthreads();

    // ---- B: scores via exact tanh addition identity (reg tA)
    {
      float acc = 0.f;
#pragma unroll
      for (int jj = 0; jj < 8; jj++) {
        float4 A4 = tB4[jj];
        float4 U4 = *(const float4*)(tu_pB + jj * 4);
        float4 W4 = *(const float4*)(we_pB + jj * 4);
        acc = fmaf((A4.x + U4.x) * frcp(fmaxf(fmaf(A4.x, U4.x, 1.f), 1e-6f)), W4.x, acc);
        acc = fmaf((A4.y + U4.y) * frcp(fmaxf(fmaf(A4.y, U4.y, 1.f), 1e-6f)), W4.y, acc);
        acc = fmaf((A4.z + U4.z) * frcp(fmaxf(fmaf(A4.z, U4.z, 1.f), 1e-6f)), W4.z, acc);
        acc = fmaf((A4.w + U4.w) * frcp(fmaxf(fmaf(A4.w, U4.w, 1.f), 1e-6f)), W4.w, acc);
      }
      acc += __shfl_xor(acc, 1);
      acc += __shfl_xor(acc, 2);
      if (hgB == 0) sc_s[SCIDX(qB)] = acc + web_r;
    }
    __syncthreads();

    // ---- C (per-wave redundant softmax stats) + D (alpha) fused
    {
      const int lane = t & 63;
      float s0 = sc_s[SCIDX(lane)];
      float s1 = sc_s[SCIDX(lane + 64)];
      float s2 = sc_s[SCIDX(lane + 128)];
      float s3 = sc_s[SCIDX(lane + 192)];
      float mx = fmaxf(fmaxf(s0, s1), fmaxf(s2, s3));
#pragma unroll
      for (int d = 1; d < 64; d <<= 1) mx = fmaxf(mx, __shfl_xor(mx, d));
      float sum = __expf(s0 - mx) + __expf(s1 - mx) + __expf(s2 - mx) + __expf(s3 - mx);
#pragma unroll
      for (int d = 1; d < 64; d <<= 1) sum += __shfl_xor(sum, d);
      float inv = frcp(sum);
      float acc = 0.f;
#pragma unroll
      for (int r = 0; r < 32; r++) {   // q = qgD + 8r (interleaved, bank-clean)
        float e = __expf(sc_pD[(r >> 2) * 36 + (r & 3) * 8] - mx);
        acc = fmaf(e, whs_p[r * 1056], acc);
      }
      acc += __shfl_xor(acc, 1);
      acc += __shfl_xor(acc, 2);
      acc += __shfl_xor(acc, 4);
      if (qgD == 0) alpha_s[AIDX(hD)] = acc * inv;
    }
    __syncthreads();

    // ---- E: gate = sigmoid(Wg[:, :128] @ alpha + Gp) ; xh = gate * [alpha;p]
    {
      float acc = 0.f;
#pragma unroll
      for (int rr = 0; rr < 8; rr++) {
        float4 a4 = *(const float4*)(al_pE + rr * 4);
        acc = fmaf(wE[rr * 4 + 0], a4.x, acc);
        acc = fmaf(wE[rr * 4 + 1], a4.y, acc);
        acc = fmaf(wE[rr * 4 + 2], a4.z, acc);
        acc = fmaf(wE[rr * 4 + 3], a4.w, acc);
      }
      acc += __shfl_xor(acc, 1);
      acc += __shfl_xor(acc, 2);
      if (kgE == 0) {
        float g = gp_c + acc;
        float sg = 1.0f / (1.0f + __expf(-g));
        float xv = (iE < 128) ? alpha_s[aIdxE] : pf_c;
        xh_s[iE] = sg * xv;
      }
    }
    __syncthreads();

    // ---- F: gates = WT @ [xh; h]  (only streamed weights: 768KB/step)
    {
      const float* Wb = WTp + (size_t)(kgF * 48) * 2048 + iF * 4;
      const float* xb = xh_s + kgF * 192;
      float acc = 0.f;
#pragma unroll 4
      for (int r4 = 0; r4 < 48; r4++) {
        float4 w4 = *(const float4*)(Wb + (size_t)r4 * 2048);
        float4 x4 = *(const float4*)(xb + r4 * 4);
        acc = fmaf(w4.x, x4.x, acc);
        acc = fmaf(w4.y, x4.y, acc);
        acc = fmaf(w4.z, x4.z, acc);
        acc = fmaf(w4.w, x4.w, acc);
      }
      acc += __shfl_xor(acc, 1);
      if (kgF == 0) gates_s[iF] = acc + bb_r;
    }
    __syncthreads();

    // ---- G: LSTM cell (i,f,g,o), c in registers
    if (t < 128) {
      float gi = gates_s[t],       gf = gates_s[128 + t];
      float gg = gates_s[256 + t], go = gates_s[384 + t];
      float iv = 1.0f / (1.0f + __expf(-gi));
      float fv = 1.0f / (1.0f + __expf(-gf));
      float gv = tanhf(gg);
      float ov = 1.0f / (1.0f + __expf(-go));
      float cn = fmaf(fv, c_r, iv * gv);
      float hn = ov * tanhf(cn);
      c_r = cn;
      h_s[HIDX(t)] = hn;
      xh_s[256 + t] = hn;
      out[((size_t)b * 128 + st) * 128 + t] = hn;
    }
    wht_c = wht_n; gp_c = gp_n; pf_c = pf_n;
    __syncthreads();
  }
}

// ----------------------------------------------------------------- launcher
extern "C" void kernel_launch(void* const* d_in, const int* in_sizes, int n_in,
                              void* d_out, int out_size, void* d_ws, size_t ws_size,
                              hipStream_t stream) {
  static const int SZ_DICT[18] = {262144, 524288, 16384, 128, 16384, 128,
                                  16384, 128, 128, 1, 65536, 256,
                                  131072, 65536, 512, 512, 2048, 4096};
  static const int ALPHA2DICT[18] = {9, 8, 11, 10, 13, 12, 7, 6, 3, 2, 5, 4,
                                     15, 14, 0, 16, 1, 17};
  const void* in[18];
  for (int i = 0; i < 18; i++) in[i] = (i < n_in) ? d_in[i] : nullptr;

  bool dict_ok = true;
  int lim = (n_in < 16) ? n_in : 16;
  for (int i = 0; i < lim; i++) if (in_sizes[i] != SZ_DICT[i]) dict_ok = false;
  if (!dict_ok) {
    bool alpha_ok = true;
    for (int s = 0; s < n_in && s < 18; s++)
      if (in_sizes[s] != SZ_DICT[ALPHA2DICT[s]]) alpha_ok = false;
    if (alpha_ok)
      for (int s = 0; s < n_in && s < 18; s++) in[ALPHA2DICT[s]] = d_in[s];
  }

  const void* p   = in[0];  const void* q   = in[1];
  const void* Wsw = in[2];  const void* Wsb = in[3];
  const void* Wtw = in[4];  const void* Wtb = in[5];
  const void* Wrw = in[6];  const void* Wrb = in[7];
  const void* Wew = in[8];  const void* Web = in[9];
  const void* Wgw = in[10]; const void* Wgb = in[11];
  const void* Wih = in[12]; const void* Whh = in[13];
  const void* bih = in[14]; const void* bhh = in[15];

  float* ws = (float*)d_ws;
  float* whs  = ws;                      // 524288
  float* tA   = whs + 524288;            // 524288
  float* pf   = tA + 524288;             // 262144
  float* wht  = pf + 262144;             // 262144
  float* Gp   = wht + 262144;            // 524288
  float* WrT  = Gp + 524288;             // 16384
  float* WgT  = WrT + 16384;             // 65536
  float* WTp  = WgT + 65536;             // 196608
  float* bb   = WTp + 196608;            // 512
  float* wrb  = bb + 512;                // 128
  float* wew  = wrb + 128;               // 128
  float* web  = wew + 128;               // 4 (1 used)
  float* wgb  = web + 4;                 // 256
  uint32_t* flag = (uint32_t*)(wgb + 256);  // ~9.5 MB total

  hipLaunchKernelGGL(detect_kernel, dim3(1), dim3(256), 0, stream,
                     (const uint16_t*)q, flag);
  hipLaunchKernelGGL(pack2, dim3(2117), dim3(256), 0, stream,
                     p, Wrw, Wrb, Wew, Web, Wgw, Wih, Whh, bih, bhh,
                     pf, WrT, wrb, wew, web, WgT, wgb, WTp, bb, Wgb, flag);
  // whs = q@Ws^T + Ws_b : 4096 rows x 128
  hipLaunchKernelGGL(gemm_rw, dim3(256), dim3(256), 0, stream,
                     q, 128, Wsw, 128, 0, Wsb, whs, 128, flag);
  // wht = p@Wt^T + Wt_b : 2048 rows x 128
  hipLaunchKernelGGL(gemm_rw, dim3(128), dim3(256), 0, stream,
                     p, 128, Wtw, 128, 0, Wtb, wht, 128, flag);
  // Gp = p@Wg[:,128:]^T + Wg_b : 2048 rows x 256
  hipLaunchKernelGGL(gemm_rw, dim3(128), dim3(256), 0, stream,
                     p, 128, Wgw, 256, 128, Wgb, Gp, 256, flag);
  hipLaunchKernelGGL(tanh_whs, dim3(2048), dim3(256), 0, stream, whs, tA);
  hipLaunchKernelGGL(mlstm_seq4, dim3(16), dim3(1024), 0, stream,
                     pf, whs, tA, wht, Gp, WrT, wrb, wew, web, WgT, WTp, bb,
                     (float*)d_out);
}

// Round 2
// 1657.079 us; speedup vs baseline: 1.4960x; 1.4960x over previous
//
#include <hip/hip_runtime.h>
#include <cstdint>

// mLstm  B=16, P=128, Q=256, D=128, H=128. fp32 in/out (verified R4/R5).
// R7: 4 blocks per batch (64 blocks, cooperative launch). Cross-block split of
// pass B (q-slice), pass F (gate-row slice: WTp stream 768->192KB/step/CU) and
// the LSTM cell; A/softmax/D/E redundant per block. 2 device-scope group
// barriers per step (score exchange, h exchange; h double-buffered by parity).
// Spill fix from R6 post-mortem: amdgpu_waves_per_eu(4,4) pins the VGPR budget
// at 128 (launch_bounds(1024,4) let the backend target 8 waves/EU = 64 VGPRs
// and spill all resident arrays to scratch). Residency trimmed to 56 f/thread.

__device__ __forceinline__ float bf2f(uint16_t u) {
  uint32_t x = ((uint32_t)u) << 16; float f; __builtin_memcpy(&f, &x, 4); return f;
}
__device__ __forceinline__ float load_in(const void* p, size_t i, int f32) {
  return f32 ? ((const float*)p)[i] : bf2f(((const uint16_t*)p)[i]);
}
__device__ __forceinline__ float frcp(float x) { return __builtin_amdgcn_rcpf(x); }

__device__ __forceinline__ void st_agent(float* p, float v) {
  __hip_atomic_store(p, v, __ATOMIC_RELAXED, __HIP_MEMORY_SCOPE_AGENT);
}
__device__ __forceinline__ float ld_agent(const float* p) {
  return __hip_atomic_load(p, __ATOMIC_RELAXED, __HIP_MEMORY_SCOPE_AGENT);
}
// 4-member group barrier. Producer waves drain their agent-scope stores before
// s_barrier (compiler-inserted vmcnt(0)); leader release-adds, spins acquire.
__device__ __forceinline__ void gbar4(uint32_t* c) {
  __syncthreads();
  if (threadIdx.x == 0) {
    __hip_atomic_fetch_add(c, 1u, __ATOMIC_RELEASE, __HIP_MEMORY_SCOPE_AGENT);
    while (__hip_atomic_load(c, __ATOMIC_ACQUIRE, __HIP_MEMORY_SCOPE_AGENT) < 4u)
      __builtin_amdgcn_s_sleep(1);
  }
  __syncthreads();
}

// ------------------------------------------------------------- detect kernel
__global__ void detect_kernel(const uint16_t* __restrict__ q16,
                              uint32_t* __restrict__ flag) {
  __shared__ int cnt;
  if (threadIdx.x == 0) cnt = 0;
  __syncthreads();
  int bad = 0;
  for (int i = threadIdx.x; i < 4096; i += 256) {
    int e = (q16[i] >> 7) & 0xFF;
    if (e > 0x8A) bad++;
  }
  atomicAdd(&cnt, bad);
  __syncthreads();
  if (threadIdx.x == 0) *flag = (cnt > 16) ? 1u : 0u;
}

// ------------------------------------------------- convert + transpose pack
// pf[262144]=p; WrT[k*128+j]=Wr[j][k]; wrb[128]; wew[128]; web[1];
// WgT[k*256+i]=Wg[i][k]; wgb[256];
// WTp k4-major float4 pack: WTp[k4*2048 + i*4 + c] = WT[k4*4+c][i];
// bb[512]=bih+bhh.  Appended: zero h_ex[4096], zero ctr[4096].
__global__ void pack2(const void* __restrict__ p,
                      const void* __restrict__ Wr,  const void* __restrict__ Wrb_,
                      const void* __restrict__ Wew_, const void* __restrict__ Web_,
                      const void* __restrict__ Wg,
                      const void* __restrict__ Wih, const void* __restrict__ Whh,
                      const void* __restrict__ bih, const void* __restrict__ bhh,
                      float* __restrict__ pf,
                      float* __restrict__ WrT, float* __restrict__ wrb,
                      float* __restrict__ wew, float* __restrict__ web,
                      float* __restrict__ WgT, float* __restrict__ wgb,
                      float* __restrict__ WTp, float* __restrict__ bb,
                      const void* __restrict__ Wgb_,
                      const uint32_t* __restrict__ flag,
                      float* __restrict__ hexz, uint32_t* __restrict__ ctrz) {
  const int f32 = (int)*flag;
  long idx = (long)blockIdx.x * blockDim.x + threadIdx.x;
  if (idx < 262144) { pf[idx] = load_in(p, idx, f32); return; }
  idx -= 262144;
  if (idx < 16384) { int k = idx >> 7, j = idx & 127;
    WrT[idx] = load_in(Wr, (size_t)j * 128 + k, f32); return; }
  idx -= 16384;
  if (idx < 128) { wrb[idx] = load_in(Wrb_, idx, f32); return; }
  idx -= 128;
  if (idx < 128) { wew[idx] = load_in(Wew_, idx, f32); return; }
  idx -= 128;
  if (idx < 1) { web[0] = load_in(Web_, 0, f32); return; }
  idx -= 1;
  if (idx < 65536) { int k = idx >> 8, i = idx & 255;
    WgT[idx] = load_in(Wg, (size_t)i * 256 + k, f32); return; }
  idx -= 65536;
  if (idx < 256) { wgb[idx] = load_in(Wgb_, idx, f32); return; }
  idx -= 256;
  if (idx < 196608) {
    int k4 = idx >> 11, i = (idx >> 2) & 511, c = idx & 3;
    int k = k4 * 4 + c;
    WTp[idx] = (k < 256) ? load_in(Wih, (size_t)i * 256 + k, f32)
                         : load_in(Whh, (size_t)i * 128 + (k - 256), f32);
    return; }
  idx -= 196608;
  if (idx < 512) { bb[idx] = load_in(bih, idx, f32) + load_in(bhh, idx, f32); return; }
  idx -= 512;
  if (idx < 4096) { hexz[idx] = 0.f; return; }
  idx -= 4096;
  if (idx < 4096) { ctrz[idx] = 0u; return; }
}

// ------------------------------------------------------------ small GEMM
__global__ __launch_bounds__(256) void gemm_rw(const void* __restrict__ A, int lda,
                                               const void* __restrict__ W, int ldw,
                                               int w_off,
                                               const void* __restrict__ bias,
                                               float* __restrict__ out, int C,
                                               const uint32_t* __restrict__ flag) {
  __shared__ float A_l[16][128];
  __shared__ float W_l[64][129];
  const int f32 = (int)*flag;
  const int t = threadIdx.x;
  const int r0 = blockIdx.x * 16;
  for (int idx = t; idx < 16 * 128; idx += 256) {
    int rr = idx >> 7, kk = idx & 127;
    A_l[rr][kk] = load_in(A, (size_t)(r0 + rr) * lda + kk, f32);
  }
  const int c_l = t & 63, rg = t >> 6;
  for (int c0 = 0; c0 < C; c0 += 64) {
    __syncthreads();
    for (int idx = t; idx < 64 * 128; idx += 256) {
      int cc = idx >> 7, kk = idx & 127;
      W_l[cc][kk] = load_in(W, (size_t)w_off + (size_t)(c0 + cc) * ldw + kk, f32);
    }
    __syncthreads();
    float acc[4] = {0.f, 0.f, 0.f, 0.f};
    for (int k = 0; k < 128; k++) {
      float w = W_l[c_l][k];
#pragma unroll
      for (int x = 0; x < 4; x++) acc[x] = fmaf(A_l[rg * 4 + x][k], w, acc[x]);
    }
    float bv = load_in(bias, c0 + c_l, f32);
#pragma unroll
    for (int x = 0; x < 4; x++)
      out[(size_t)(r0 + rg * 4 + x) * C + c0 + c_l] = acc[x] + bv;
  }
}

// tA = tanh(whs)
__global__ void tanh_whs(const float* __restrict__ whs, float* __restrict__ tA) {
  int i = blockIdx.x * blockDim.x + threadIdx.x;
  tA[i] = tanhf(whs[i]);
}

// ---------------------------------------------------------- sequential kernel
// 64 blocks x 1024 threads; group = batch b = blockIdx&15, slice k = blockIdx>>4
// (members of a group are 16 apart -> same XCD under round-robin dispatch).
#define TUIDX(j) ((((j) >> 5) * 36) + ((j) & 31))
#define AIDX(h)  ((((h) >> 5) * 36) + ((h) & 31))
#define HIDX(k)  ((((k) >> 4) * 20) + ((k) & 15))
#define XIDX(i)  ((((i) / 48) * 52) + ((i) % 48))

__global__ __launch_bounds__(1024) __attribute__((amdgpu_waves_per_eu(4, 4)))
void mlstm_seq5(const float* __restrict__ pf,    // [16][128][128]
                const float* __restrict__ whs,   // [16][256][128]
                const float* __restrict__ tA_g,  // [16][256][128]
                const float* __restrict__ wht_g, // [16][128][128]
                const float* __restrict__ Gp_g,  // [16][128][256]
                const float* __restrict__ WrT,   // [128][128] k-major
                const float* __restrict__ wrb,   // [128]
                const float* __restrict__ wew,   // [128]
                const float* __restrict__ web,   // [1]
                const float* __restrict__ WgT,   // [256][256] k-major
                const float* __restrict__ WTp,   // [96][512][4] k4-major pack
                const float* __restrict__ bb,    // [512]
                float* __restrict__ h_ex,        // [2][16][128] parity exchange
                float* __restrict__ sc_ex,       // [16][256] score exchange
                uint32_t* __restrict__ ctr,      // [16][128][2] barrier counters
                float* __restrict__ out) {       // [16][128][128]
  const int b = blockIdx.x & 15, kblk = blockIdx.x >> 4, t = threadIdx.x;

  __shared__ __align__(16) float whs_l[256 * 132];   // 135168 B padded rows
  __shared__ __align__(16) float tu_s[144];
  __shared__ __align__(16) float wew_s[144];
  __shared__ __align__(16) float e_s[256];
  __shared__ __align__(16) float alpha_s[144];
  __shared__ __align__(16) float xh_s[8 * 52];       // 48-chunks at stride 52
  __shared__ __align__(16) float h_s[160];
  __shared__ __align__(16) float gates_s[128];
  __shared__ float inv_s;

  const float* whs_b = whs + (size_t)b * 32768;

  // pass thread mappings (reduction groups = consecutive lanes -> shfl)
  const int jA = t >> 3, kgA = t & 7;              // A: 128 j x 8 kg(16 k)
  const int qB = (kblk << 6) + (t >> 4), hgB = t & 15; // B: 64-q slice x 16 hg(8 h)
  const int hD = t >> 3, qgD = t & 7;              // D: 128 h x 8 qg(32 q il.)
  const int iE = t >> 2, kgE = t & 3;              // E: 256 i x 4 kg(32 k)
  const int iF = t >> 3, kgF = t & 7;              // F: 128 rows x 8 kg(48 k)
  const int rowF = ((iF >> 5) << 7) + (kblk << 5) + (iF & 31); // gate row in WT

  // ---- LDS init
  for (int idx = t; idx < 32768; idx += 1024)
    whs_l[(idx >> 7) * 132 + (idx & 127)] = whs_b[idx];
  if (t < 128) wew_s[TUIDX(t)] = wew[t];

  // ---- register-resident (56 floats/thread; budget pinned at 128 VGPR)
  float wA[16];
#pragma unroll
  for (int r = 0; r < 16; r++)
    wA[r] = WrT[(size_t)(kgA * 16 + r) * 128 + jA];
  const float4 tBa = *(const float4*)(tA_g + (size_t)b * 32768 + (size_t)qB * 128 + hgB * 8);
  const float4 tBb = *(const float4*)(tA_g + (size_t)b * 32768 + (size_t)qB * 128 + hgB * 8 + 4);
  float wE[32];
#pragma unroll
  for (int r = 0; r < 32; r++)
    wE[r] = WgT[(size_t)(kgE * 32 + r) * 256 + iE];

  const float web_r = web[0];
  const float wrb_r = wrb[jA];
  const float bbF_r = bb[rowF];
  float c_r = 0.f;                        // t<32 owners: c for h = kblk*32+t

  const int xIdxE = XIDX(iE);
  const int aIdxE = AIDX(iE & 127);
  const int xIdxH = XIDX(256 + (t & 127));
  float* scex = sc_ex + b * 256;
  uint32_t* ctr_b = ctr + b * 256;

  // per-step prefetch registers
  float wht_c = (kgA == 0) ? wht_g[((size_t)b * 128 + 0) * 128 + jA] : 0.f;
  float gp_c  = (kgE == 0) ? Gp_g[((size_t)b * 128 + 0) * 256 + iE] : 0.f;
  float pf_c  = (kgE == 0 && iE >= 128) ? pf[((size_t)b * 128 + 0) * 128 + (iE - 128)] : 0.f;

  __syncthreads();

  for (int st = 0; st < 128; st++) {
    const int st1 = (st < 127) ? st + 1 : 127;
    float wht_n = (kgA == 0) ? wht_g[((size_t)b * 128 + st1) * 128 + jA] : 0.f;
    float gp_n  = (kgE == 0) ? Gp_g[((size_t)b * 128 + st1) * 256 + iE] : 0.f;
    float pf_n  = (kgE == 0 && iE >= 128) ? pf[((size_t)b * 128 + st1) * 128 + (iE - 128)] : 0.f;

    // ---- h load (parity st&1; zeros at st=0)
    if (t < 128) {
      float hv = ld_agent(h_ex + (st & 1) * 2048 + b * 128 + t);
      h_s[HIDX(t)] = hv;
      xh_s[xIdxH] = hv;
    }
    __syncthreads();

    // ---- A: tu = tanh(h@Wr^T + wrb + wht)   [redundant]
    {
      float acc = 0.f;
#pragma unroll
      for (int rr = 0; rr < 4; rr++) {
        float4 h4 = *(const float4*)(h_s + kgA * 20 + rr * 4);
        acc = fmaf(h4.x, wA[rr * 4 + 0], acc);
        acc = fmaf(h4.y, wA[rr * 4 + 1], acc);
        acc = fmaf(h4.z, wA[rr * 4 + 2], acc);
        acc = fmaf(h4.w, wA[rr * 4 + 3], acc);
      }
      acc += __shfl_xor(acc, 1);
      acc += __shfl_xor(acc, 2);
      acc += __shfl_xor(acc, 4);
      if (kgA == 0) tu_s[TUIDX(jA)] = tanhf(acc + wrb_r + wht_c);
    }
    __syncthreads();

    // ---- B: scores for q-slice via tanh addition identity  [split 4-way]
    {
      const float* tu_p = tu_s + TUIDX(hgB * 8);
      const float* we_p = wew_s + TUIDX(hgB * 8);
      float acc = 0.f;
      {
        float4 A4 = tBa, U4 = *(const float4*)(tu_p), W4 = *(const float4*)(we_p);
        acc = fmaf((A4.x + U4.x) * frcp(fmaxf(fmaf(A4.x, U4.x, 1.f), 1e-6f)), W4.x, acc);
        acc = fmaf((A4.y + U4.y) * frcp(fmaxf(fmaf(A4.y, U4.y, 1.f), 1e-6f)), W4.y, acc);
        acc = fmaf((A4.z + U4.z) * frcp(fmaxf(fmaf(A4.z, U4.z, 1.f), 1e-6f)), W4.z, acc);
        acc = fmaf((A4.w + U4.w) * frcp(fmaxf(fmaf(A4.w, U4.w, 1.f), 1e-6f)), W4.w, acc);
      }
      {
        float4 A4 = tBb, U4 = *(const float4*)(tu_p + 4), W4 = *(const float4*)(we_p + 4);
        acc = fmaf((A4.x + U4.x) * frcp(fmaxf(fmaf(A4.x, U4.x, 1.f), 1e-6f)), W4.x, acc);
        acc = fmaf((A4.y + U4.y) * frcp(fmaxf(fmaf(A4.y, U4.y, 1.f), 1e-6f)), W4.y, acc);
        acc = fmaf((A4.z + U4.z) * frcp(fmaxf(fmaf(A4.z, U4.z, 1.f), 1e-6f)), W4.z, acc);
        acc = fmaf((A4.w + U4.w) * frcp(fmaxf(fmaf(A4.w, U4.w, 1.f), 1e-6f)), W4.w, acc);
      }
      acc += __shfl_xor(acc, 1);
      acc += __shfl_xor(acc, 2);
      acc += __shfl_xor(acc, 4);
      acc += __shfl_xor(acc, 8);
      if (hgB == 0) st_agent(scex + qB, acc + web_r);
    }
    gbar4(ctr_b + st * 2);

    // ---- softmax (t<64): gather 256 scores, e_s + inv  [redundant]
    if (t < 64) {
      float s0 = ld_agent(scex + t),       s1 = ld_agent(scex + t + 64);
      float s2 = ld_agent(scex + t + 128), s3 = ld_agent(scex + t + 192);
      float mx = fmaxf(fmaxf(s0, s1), fmaxf(s2, s3));
#pragma unroll
      for (int d = 1; d < 64; d <<= 1) mx = fmaxf(mx, __shfl_xor(mx, d));
      float e0 = __expf(s0 - mx), e1 = __expf(s1 - mx),
            e2 = __expf(s2 - mx), e3 = __expf(s3 - mx);
      float sum = e0 + e1 + e2 + e3;
#pragma unroll
      for (int d = 1; d < 64; d <<= 1) sum += __shfl_xor(sum, d);
      e_s[t] = e0; e_s[t + 64] = e1; e_s[t + 128] = e2; e_s[t + 192] = e3;
      if (t == 0) inv_s = 1.0f / sum;
    }
    __syncthreads();

    // ---- D: alpha = (sum_q e[q]*whs[q][h]) * inv   [redundant, whs in LDS]
    {
      const float* whs_p = whs_l + qgD * 132 + hD;
      float acc = 0.f;
#pragma unroll 8
      for (int r = 0; r < 32; r++)       // q = qgD + 8r
        acc = fmaf(e_s[qgD + 8 * r], whs_p[r * 1056], acc);
      acc += __shfl_xor(acc, 1);
      acc += __shfl_xor(acc, 2);
      acc += __shfl_xor(acc, 4);
      if (qgD == 0) alpha_s[AIDX(hD)] = acc * inv_s;
    }
    __syncthreads();

    // ---- E: gate = sigmoid(Wg[:,:128]@alpha + Gp); xh = gate*[alpha;p] [red.]
    {
      float acc = 0.f;
#pragma unroll
      for (int rr = 0; rr < 8; rr++) {
        float4 a4 = *(const float4*)(alpha_s + kgE * 36 + rr * 4);
        acc = fmaf(wE[rr * 4 + 0], a4.x, acc);
        acc = fmaf(wE[rr * 4 + 1], a4.y, acc);
        acc = fmaf(wE[rr * 4 + 2], a4.z, acc);
        acc = fmaf(wE[rr * 4 + 3], a4.w, acc);
      }
      acc += __shfl_xor(acc, 1);
      acc += __shfl_xor(acc, 2);
      if (kgE == 0) {
        float g = gp_c + acc;
        float sg = 1.0f / (1.0f + __expf(-g));
        float xv = (iE < 128) ? alpha_s[aIdxE] : pf_c;
        xh_s[xIdxE] = sg * xv;
      }
    }
    __syncthreads();

    // ---- F: gates slice = WT[rows]@[xh;h]  [split 4-way: 192KB/step stream]
    {
      const float* Wb = WTp + (size_t)rowF * 4 + (size_t)(kgF * 12) * 2048;
      const float* xb = xh_s + kgF * 52;
      float acc = 0.f;
#pragma unroll
      for (int r4 = 0; r4 < 12; r4++) {
        float4 w4 = *(const float4*)(Wb + (size_t)r4 * 2048);
        float4 x4 = *(const float4*)(xb + r4 * 4);
        acc = fmaf(w4.x, x4.x, acc);
        acc = fmaf(w4.y, x4.y, acc);
        acc = fmaf(w4.z, x4.z, acc);
        acc = fmaf(w4.w, x4.w, acc);
      }
      acc += __shfl_xor(acc, 1);
      acc += __shfl_xor(acc, 2);
      acc += __shfl_xor(acc, 4);
      if (kgF == 0) gates_s[iF] = acc + bbF_r;
    }
    __syncthreads();

    // ---- cell: 32-h slice; publish h for next step  [split 4-way]
    if (t < 32) {
      float gi = gates_s[t],      gf = gates_s[32 + t];
      float gg = gates_s[64 + t], go = gates_s[96 + t];
      float iv = 1.0f / (1.0f + __expf(-gi));
      float fv = 1.0f / (1.0f + __expf(-gf));
      float gv = tanhf(gg);
      float ov = 1.0f / (1.0f + __expf(-go));
      float cn = fmaf(fv, c_r, iv * gv);
      float hn = ov * tanhf(cn);
      c_r = cn;
      st_agent(h_ex + ((st + 1) & 1) * 2048 + b * 128 + (kblk * 32 + t), hn);
      out[((size_t)b * 128 + st) * 128 + kblk * 32 + t] = hn;
    }
    gbar4(ctr_b + st * 2 + 1);

    wht_c = wht_n; gp_c = gp_n; pf_c = pf_n;
  }
}

// ----------------------------------------------------------------- launcher
extern "C" void kernel_launch(void* const* d_in, const int* in_sizes, int n_in,
                              void* d_out, int out_size, void* d_ws, size_t ws_size,
                              hipStream_t stream) {
  static const int SZ_DICT[18] = {262144, 524288, 16384, 128, 16384, 128,
                                  16384, 128, 128, 1, 65536, 256,
                                  131072, 65536, 512, 512, 2048, 4096};
  static const int ALPHA2DICT[18] = {9, 8, 11, 10, 13, 12, 7, 6, 3, 2, 5, 4,
                                     15, 14, 0, 16, 1, 17};
  const void* in[18];
  for (int i = 0; i < 18; i++) in[i] = (i < n_in) ? d_in[i] : nullptr;

  bool dict_ok = true;
  int lim = (n_in < 16) ? n_in : 16;
  for (int i = 0; i < lim; i++) if (in_sizes[i] != SZ_DICT[i]) dict_ok = false;
  if (!dict_ok) {
    bool alpha_ok = true;
    for (int s = 0; s < n_in && s < 18; s++)
      if (in_sizes[s] != SZ_DICT[ALPHA2DICT[s]]) alpha_ok = false;
    if (alpha_ok)
      for (int s = 0; s < n_in && s < 18; s++) in[ALPHA2DICT[s]] = d_in[s];
  }

  const void* p   = in[0];  const void* q   = in[1];
  const void* Wsw = in[2];  const void* Wsb = in[3];
  const void* Wtw = in[4];  const void* Wtb = in[5];
  const void* Wrw = in[6];  const void* Wrb = in[7];
  const void* Wew = in[8];  const void* Web = in[9];
  const void* Wgw = in[10]; const void* Wgb = in[11];
  const void* Wih = in[12]; const void* Whh = in[13];
  const void* bih = in[14]; const void* bhh = in[15];

  float* ws = (float*)d_ws;
  float* whs  = ws;                      // 524288
  float* tA   = whs + 524288;            // 524288
  float* pff  = tA + 524288;             // 262144
  float* wht  = pff + 262144;            // 262144
  float* Gp   = wht + 262144;            // 524288
  float* WrT  = Gp + 524288;             // 16384
  float* WgT  = WrT + 16384;             // 65536
  float* WTp  = WgT + 65536;             // 196608
  float* bb   = WTp + 196608;            // 512
  float* wrb  = bb + 512;                // 128
  float* wew  = wrb + 128;               // 128
  float* web  = wew + 128;               // 4 (1 used)
  float* wgb  = web + 4;                 // 256
  uint32_t* flag = (uint32_t*)(wgb + 256);  // 4
  float* h_ex = (float*)(flag + 4);      // 4096 (2 parities x 16 x 128)
  uint32_t* ctrp = (uint32_t*)(h_ex + 4096); // 4096 (16 x 128 x 2)
  float* sc_ex = (float*)(ctrp + 4096);  // 4096 (16 x 256)   ~9.6 MB total

  hipLaunchKernelGGL(detect_kernel, dim3(1), dim3(256), 0, stream,
                     (const uint16_t*)q, flag);
  hipLaunchKernelGGL(pack2, dim3(2149), dim3(256), 0, stream,
                     p, Wrw, Wrb, Wew, Web, Wgw, Wih, Whh, bih, bhh,
                     pff, WrT, wrb, wew, web, WgT, wgb, WTp, bb, Wgb, flag,
                     h_ex, ctrp);
  // whs = q@Ws^T + Ws_b : 4096 rows x 128
  hipLaunchKernelGGL(gemm_rw, dim3(256), dim3(256), 0, stream,
                     q, 128, Wsw, 128, 0, Wsb, whs, 128, flag);
  // wht = p@Wt^T + Wt_b : 2048 rows x 128
  hipLaunchKernelGGL(gemm_rw, dim3(128), dim3(256), 0, stream,
                     p, 128, Wtw, 128, 0, Wtb, wht, 128, flag);
  // Gp = p@Wg[:,128:]^T + Wg_b : 2048 rows x 256
  hipLaunchKernelGGL(gemm_rw, dim3(128), dim3(256), 0, stream,
                     p, 128, Wgw, 256, 128, Wgb, Gp, 256, flag);
  hipLaunchKernelGGL(tanh_whs, dim3(2048), dim3(256), 0, stream, whs, tA);

  float* outf = (float*)d_out;
  void* kargs[16] = {
    (void*)&pff, (void*)&whs, (void*)&tA, (void*)&wht, (void*)&Gp,
    (void*)&WrT, (void*)&wrb, (void*)&wew, (void*)&web, (void*)&WgT,
    (void*)&WTp, (void*)&bb, (void*)&h_ex, (void*)&sc_ex, (void*)&ctrp,
    (void*)&outf
  };
  hipLaunchCooperativeKernel((const void*)mlstm_seq5, dim3(64), dim3(1024),
                             kargs, 0, stream);
}